// Round 1
// baseline (1219.115 us; speedup 1.0000x reference)
//
#include <hip/hip_runtime.h>

namespace {

constexpr int SEQ = 2048, BATCH = 1024, IN = 10, H = 20;
constexpr int WB = 3;                         // batch elems per (one-wave) block
constexpr int XS = 32;                        // x steps staged in LDS per chunk
constexpr int NBLK = (BATCH + WB - 1) / WB;   // 342
constexpr int XE = XS * WB * IN;              // 960 floats per chunk
constexpr int XPL = XE / 64;                  // 15 elements per lane

__device__ __forceinline__ float sigf(float x) {
    return 1.0f / (1.0f + __expf(-x));
}
// overflow-safe tanh: 1 - 2/(1+exp(2x))
__device__ __forceinline__ float tanh_fast(float x) {
    return 1.0f - 2.0f / (1.0f + __expf(2.0f * x));
}

__launch_bounds__(64)
__global__ void lstm_bidir(const float* __restrict__ x,
                           const float* __restrict__ h0,
                           const float* __restrict__ c0,
                           const float* __restrict__ w_ih_f, const float* __restrict__ w_hh_f,
                           const float* __restrict__ b_ih_f, const float* __restrict__ b_hh_f,
                           const float* __restrict__ w_ih_b, const float* __restrict__ w_hh_b,
                           const float* __restrict__ b_ih_b, const float* __restrict__ b_hh_b,
                           float* __restrict__ out, float* __restrict__ h_n, float* __restrict__ c_n)
{
    const int dir  = blockIdx.y;
    const int b0   = blockIdx.x * WB;
    const int lane = threadIdx.x;
    const int bl   = lane / H;                 // 0..2 active, 3 for lanes 60..63
    const int u    = lane % H;
    const int blc  = bl < WB ? bl : WB - 1;    // clamped for LDS reads by idle lanes
    const int b    = b0 + bl;
    const bool active = (bl < WB) && (b < BATCH);

    const float* w_ih = dir ? w_ih_b : w_ih_f;
    const float* w_hh = dir ? w_hh_b : w_hh_f;
    const float* bi   = dir ? b_ih_b : b_ih_f;
    const float* bh   = dir ? b_hh_b : b_hh_f;

    __shared__ __align__(16) float hbuf[2][WB][H];
    __shared__ __align__(16) float xbuf[XE];

    // ---- weights fully in registers (statically indexed, fully unrolled) ----
    float whh[4][H], wih[4][IN], bia[4];
    #pragma unroll
    for (int q = 0; q < 4; ++q) {
        const int g = q * H + u;
        #pragma unroll
        for (int k = 0; k < H; ++k) whh[q][k] = w_hh[g * H + k];
        #pragma unroll
        for (int k = 0; k < IN; ++k) wih[q][k] = w_ih[g * IN + k];
        bia[q] = bi[g] + bh[g];
    }

    float c = 0.0f, hlast = 0.0f;
    if (active) {
        c = c0[(dir * BATCH + b) * H + u];
        hbuf[0][bl][u] = h0[(dir * BATCH + b) * H + u];
    }

    // ---- x staging: LDS chunk of XS steps, register-pending prefetch of next ----
    float pend[XPL];
    auto issue_chunk = [&](int cs0) {
        #pragma unroll
        for (int i = 0; i < XPL; ++i) {
            const int e    = lane + i * 64;          // 0..959
            const int ss   = e / (WB * IN);
            const int r    = e % (WB * IN);
            const int srow = cs0 + ss;
            const int xrow = dir ? (SEQ - 1 - srow) : srow;
            const int col  = b0 * IN + r;
            pend[i] = (col < BATCH * IN) ? x[(size_t)xrow * (BATCH * IN) + col] : 0.0f;
        }
    };
    auto write_chunk = [&]() {
        #pragma unroll
        for (int i = 0; i < XPL; ++i) xbuf[lane + i * 64] = pend[i];
    };

    issue_chunk(0);
    write_chunk();
    issue_chunk(XS);       // chunk 1 in flight in registers
    __syncthreads();

    int cur = 0;
    for (int s = 0; s < SEQ; ++s) {
        const int ss = s & (XS - 1);
        if (ss == 0 && s > 0) {
            write_chunk();                         // compiler waits vmcnt before ds_write
            if (s + XS < SEQ) issue_chunk(s + XS); // next chunk hides HBM latency under 32 steps
            __syncthreads();
        }

        // h broadcast from LDS (same addr for the 20 lanes of a batch elt -> no conflicts)
        float hh[H];
        {
            const float4* hp = (const float4*)(&hbuf[cur][blc][0]);
            #pragma unroll
            for (int i = 0; i < H / 4; ++i) {
                float4 v = hp[i];
                hh[4*i] = v.x; hh[4*i+1] = v.y; hh[4*i+2] = v.z; hh[4*i+3] = v.w;
            }
        }
        float xv[IN];
        {
            const float2* xp = (const float2*)(&xbuf[(ss * WB + blc) * IN]);
            #pragma unroll
            for (int i = 0; i < IN / 2; ++i) {
                float2 v = xp[i];
                xv[2*i] = v.x; xv[2*i+1] = v.y;
            }
        }

        // 4 gates per thread: i,f,g,o (rows u, u+20, u+40, u+60 of the 80-row weights)
        float acc[4];
        #pragma unroll
        for (int q = 0; q < 4; ++q) {
            float a = bia[q];
            #pragma unroll
            for (int i = 0; i < IN; ++i) a = fmaf(xv[i], wih[q][i], a);
            #pragma unroll
            for (int k = 0; k < H; ++k) a = fmaf(hh[k], whh[q][k], a);
            acc[q] = a;
        }
        const float ig = sigf(acc[0]);
        const float fg = sigf(acc[1]);
        const float gv = tanh_fast(acc[2]);
        const float og = sigf(acc[3]);
        c = fg * c + ig * gv;
        const float h = og * tanh_fast(c);
        hlast = h;

        if (active) {
            const int orow = dir ? (SEQ - 1 - s) : s;
            out[(size_t)orow * (BATCH * 2 * H) + b * (2 * H) + dir * H + u] = h;
            hbuf[cur ^ 1][bl][u] = h;
        }
        __syncthreads();
        cur ^= 1;
    }

    if (active) {
        h_n[(dir * BATCH + b) * H + u] = hlast;
        c_n[(dir * BATCH + b) * H + u] = c;
    }
}

} // namespace

extern "C" void kernel_launch(void* const* d_in, const int* in_sizes, int n_in,
                              void* d_out, int out_size, void* d_ws, size_t ws_size,
                              hipStream_t stream)
{
    const float* x      = (const float*)d_in[0];
    const float* h0     = (const float*)d_in[1];
    const float* c0     = (const float*)d_in[2];
    const float* w_ih_f = (const float*)d_in[3];
    const float* w_hh_f = (const float*)d_in[4];
    const float* b_ih_f = (const float*)d_in[5];
    const float* b_hh_f = (const float*)d_in[6];
    const float* w_ih_b = (const float*)d_in[7];
    const float* w_hh_b = (const float*)d_in[8];
    const float* b_ih_b = (const float*)d_in[9];
    const float* b_hh_b = (const float*)d_in[10];

    float* out = (float*)d_out;
    float* h_n = out + (size_t)SEQ * BATCH * 2 * H;   // 83,886,080
    float* c_n = h_n + (size_t)2 * BATCH * H;         // +40,960

    dim3 grid(NBLK, 2), block(64);
    hipLaunchKernelGGL(lstm_bidir, grid, block, 0, stream,
                       x, h0, c0, w_ih_f, w_hh_f, b_ih_f, b_hh_f,
                       w_ih_b, w_hh_b, b_ih_b, b_hh_b, out, h_n, c_n);
}

// Round 2
// 846.666 us; speedup vs baseline: 1.4399x; 1.4399x over previous
//
#include <hip/hip_runtime.h>

namespace {

constexpr int SEQ = 2048, BATCH = 1024, IN = 10, H = 20;
constexpr int BB  = 4;                 // batch elems per block
constexpr int NT  = BB * 4 * H;        // 320 threads (80 gate-threads per batch elem)
constexpr int XS  = 32;                // x steps staged in LDS per chunk
constexpr int XE  = XS * BB * IN;      // 1280 floats per chunk
constexpr int XPL = XE / NT;           // 4 per thread
constexpr int NBLK = BATCH / BB;       // 256

__device__ __forceinline__ float rcpf(float x) { return __builtin_amdgcn_rcpf(x); }

__launch_bounds__(NT)
__global__ void lstm_bidir(const float* __restrict__ x,
                           const float* __restrict__ h0,
                           const float* __restrict__ c0,
                           const float* __restrict__ w_ih_f, const float* __restrict__ w_hh_f,
                           const float* __restrict__ b_ih_f, const float* __restrict__ b_hh_f,
                           const float* __restrict__ w_ih_b, const float* __restrict__ w_hh_b,
                           const float* __restrict__ b_ih_b, const float* __restrict__ b_hh_b,
                           float* __restrict__ out, float* __restrict__ h_n, float* __restrict__ c_n)
{
    const int dir = blockIdx.y;
    const int b0  = blockIdx.x * BB;
    const int t   = threadIdx.x;
    const int bl  = t / 80;            // 0..3  batch elem within block
    const int g   = t % 80;            // gate row 0..79
    const int q   = g / 20;            // 0=i 1=f 2=g~ 3=o
    const int u   = g % 20;            // unit
    const int b   = b0 + bl;

    const float* w_ih = dir ? w_ih_b : w_ih_f;
    const float* w_hh = dir ? w_hh_b : w_hh_f;
    const float* bi   = dir ? b_ih_b : b_ih_f;
    const float* bh   = dir ? b_hh_b : b_hh_f;

    __shared__ __align__(16) float hbuf[2][BB][H];      // h broadcast
    __shared__ __align__(16) float gbuf[BB][H][4];      // activated gates, unit-contiguous
    __shared__ __align__(16) float xbuf[XE];            // x chunk

    // ---- this thread's weight row, in registers ----
    float whh[H], wih[IN];
    #pragma unroll
    for (int k = 0; k < H; ++k) whh[k] = w_hh[g * H + k];
    #pragma unroll
    for (int k = 0; k < IN; ++k) wih[k] = w_ih[g * IN + k];
    const float bias = bi[g] + bh[g];

    // uniform nonlinearity: y = na * rcp(1 + exp(-nm*x)) + nd
    // q==2 (cell gate) -> tanh (na=2,nm=2,nd=-1); else sigmoid (1,1,0)
    const float na = (q == 2) ? 2.0f : 1.0f;
    const float nm = (q == 2) ? 2.0f : 1.0f;
    const float nd = (q == 2) ? -1.0f : 0.0f;

    float c = c0[(dir * BATCH + b) * H + u];
    if (q == 0) hbuf[0][bl][u] = h0[(dir * BATCH + b) * H + u];

    // ---- x staging ----
    float pend[XPL];
    auto issue_chunk = [&](int cs0) {
        #pragma unroll
        for (int i = 0; i < XPL; ++i) {
            const int e    = t + i * NT;            // 0..1279
            const int ss   = e / (BB * IN);
            const int r    = e % (BB * IN);
            const int srow = cs0 + ss;
            const int xrow = dir ? (SEQ - 1 - srow) : srow;
            pend[i] = x[(size_t)xrow * (BATCH * IN) + b0 * IN + r];
        }
    };
    auto write_chunk = [&]() {
        #pragma unroll
        for (int i = 0; i < XPL; ++i) xbuf[t + i * NT] = pend[i];
    };
    auto xdot_of = [&](int ss) -> float {
        const float2* xp = (const float2*)&xbuf[(ss * BB + bl) * IN];
        float a = bias;
        #pragma unroll
        for (int i = 0; i < IN / 2; ++i) {
            float2 v = xp[i];
            a = fmaf(v.x, wih[2 * i], a);
            a = fmaf(v.y, wih[2 * i + 1], a);
        }
        return a;
    };

    issue_chunk(0);
    write_chunk();
    issue_chunk(XS);

    // per-thread running out pointer (only q==3 stores)
    const ptrdiff_t ostep = dir ? -(ptrdiff_t)(BATCH * 2 * H) : (ptrdiff_t)(BATCH * 2 * H);
    float* optr = out + (size_t)(dir ? SEQ - 1 : 0) * (BATCH * 2 * H) + b * (2 * H) + dir * H + u;

    __syncthreads();

    int cur = 0;
    float h = 0.0f;

    for (int s0 = 0; s0 < SEQ; s0 += XS) {
        if (s0 > 0) {
            write_chunk();                           // waits vmcnt implicitly
            if (s0 + XS < SEQ) issue_chunk(s0 + XS);
            __syncthreads();                         // xbuf ready for this chunk
        }
        float xdot = xdot_of(0);

        for (int ss = 0; ss < XS; ++ss) {
            // ---- phase A: gate = nonlin(xdot + h . whh) ----
            float acc = xdot;
            {
                const float4* hp = (const float4*)&hbuf[cur][bl][0];
                #pragma unroll
                for (int i = 0; i < H / 4; ++i) {
                    float4 v = hp[i];
                    acc = fmaf(v.x, whh[4 * i],     acc);
                    acc = fmaf(v.y, whh[4 * i + 1], acc);
                    acc = fmaf(v.z, whh[4 * i + 2], acc);
                    acc = fmaf(v.w, whh[4 * i + 3], acc);
                }
            }
            const float ev = __expf(-nm * acc);
            gbuf[bl][u][q] = fmaf(na, rcpf(1.0f + ev), nd);
            __syncthreads();

            // ---- phase B: c/h update (redundant across q), publish h, prefetch next xdot ----
            const float4 gg = *(const float4*)&gbuf[bl][u][0];  // i,f,g~,o
            c = fmaf(gg.y, c, gg.x * gg.z);
            const float e2 = __expf(-2.0f * c);
            const float th = fmaf(2.0f, rcpf(1.0f + e2), -1.0f);
            h = gg.w * th;

            if (q == 3) {
                hbuf[cur ^ 1][bl][u] = h;
                *optr = h;
            }
            optr += ostep;
            if (ss + 1 < XS) xdot = xdot_of(ss + 1);
            __syncthreads();
            cur ^= 1;
        }
    }

    if (q == 0) {
        h_n[(dir * BATCH + b) * H + u] = h;
        c_n[(dir * BATCH + b) * H + u] = c;
    }
}

} // namespace

extern "C" void kernel_launch(void* const* d_in, const int* in_sizes, int n_in,
                              void* d_out, int out_size, void* d_ws, size_t ws_size,
                              hipStream_t stream)
{
    const float* x      = (const float*)d_in[0];
    const float* h0     = (const float*)d_in[1];
    const float* c0     = (const float*)d_in[2];
    const float* w_ih_f = (const float*)d_in[3];
    const float* w_hh_f = (const float*)d_in[4];
    const float* b_ih_f = (const float*)d_in[5];
    const float* b_hh_f = (const float*)d_in[6];
    const float* w_ih_b = (const float*)d_in[7];
    const float* w_hh_b = (const float*)d_in[8];
    const float* b_ih_b = (const float*)d_in[9];
    const float* b_hh_b = (const float*)d_in[10];

    float* out = (float*)d_out;
    float* h_n = out + (size_t)SEQ * BATCH * 2 * H;
    float* c_n = h_n + (size_t)2 * BATCH * H;

    dim3 grid(NBLK, 2), block(NT);
    hipLaunchKernelGGL(lstm_bidir, grid, block, 0, stream,
                       x, h0, c0, w_ih_f, w_hh_f, b_ih_f, b_hh_f,
                       w_ih_b, w_hh_b, b_ih_b, b_hh_b, out, h_n, c_n);
}

// Round 4
// 797.926 us; speedup vs baseline: 1.5279x; 1.0611x over previous
//
#include <hip/hip_runtime.h>

namespace {

constexpr int SEQ = 2048, BATCH = 1024, IN = 10, H = 20;
constexpr int WB   = 3;                        // batch slots per wave
constexpr int NBLK = (BATCH + WB - 1) / WB;    // 342

typedef _Float16 half2_t __attribute__((ext_vector_type(2)));

__device__ __forceinline__ float rcpf(float x) { return __builtin_amdgcn_rcpf(x); }

__device__ __forceinline__ float exp2_fast(float x) {
#if __has_builtin(__builtin_amdgcn_exp2f)
    return __builtin_amdgcn_exp2f(x);
#else
    return exp2f(x);
#endif
}

// pack two f32 -> 2xfp16 in an int (v_cvt_pkrtz_f16_f32)
__device__ __forceinline__ int pk(float a, float b) {
    auto v = __builtin_amdgcn_cvt_pkrtz(a, b);
    int i; __builtin_memcpy(&i, &v, 4); return i;
}
__device__ __forceinline__ half2_t i_as_h(int i) { half2_t h; __builtin_memcpy(&h, &i, 4); return h; }
__device__ __forceinline__ int f_as_i(float f) { int i; __builtin_memcpy(&i, &f, 4); return i; }
__device__ __forceinline__ float i_as_f(int i) { float f; __builtin_memcpy(&f, &i, 4); return f; }

__device__ __forceinline__ float dot2(int a, int b, float c) {
#if __has_builtin(__builtin_amdgcn_fdot2)
    return __builtin_amdgcn_fdot2(i_as_h(a), i_as_h(b), c, false);
#else
    half2_t ha = i_as_h(a), hb = i_as_h(b);
    return c + (float)ha.x * (float)hb.x + (float)ha.y * (float)hb.y;
#endif
}

__launch_bounds__(64)
__global__ void lstm_bidir(const float* __restrict__ x,
                           const float* __restrict__ h0,
                           const float* __restrict__ c0,
                           const float* __restrict__ w_ih_f, const float* __restrict__ w_hh_f,
                           const float* __restrict__ b_ih_f, const float* __restrict__ b_hh_f,
                           const float* __restrict__ w_ih_b, const float* __restrict__ w_hh_b,
                           const float* __restrict__ b_ih_b, const float* __restrict__ b_hh_b,
                           float* __restrict__ out, float* __restrict__ h_n, float* __restrict__ c_n)
{
    const int dir  = blockIdx.y;
    const int b0   = blockIdx.x * WB;
    const int lane = threadIdx.x;
    int slot = lane / H; if (slot >= WB) slot = WB - 1;   // lanes 60..63 mirror slot 2
    const int u    = lane % H;
    const bool active = (lane < WB * H) && (b0 + lane / H < BATCH);
    const int b    = min(b0 + slot, BATCH - 1);

    const float* w_ih = dir ? w_ih_b : w_ih_f;
    const float* w_hh = dir ? w_hh_b : w_hh_f;
    const float* bi   = dir ? b_ih_b : b_ih_f;
    const float* bh   = dir ? b_hh_b : b_hh_f;

    constexpr float L2E = 1.4426950408889634f;

    // ---- weights in registers, fp16-packed (as ints), pre-scaled by -log2e (cell gate: -2log2e) ----
    int wh[4][10]; int wi[4][5]; float bias[4];
    #pragma unroll
    for (int q = 0; q < 4; ++q) {
        const float sc = (q == 2) ? (-2.0f * L2E) : (-L2E);
        const int g = q * H + u;
        #pragma unroll
        for (int k = 0; k < 10; ++k)
            wh[q][k] = pk(w_hh[g * H + 2 * k] * sc, w_hh[g * H + 2 * k + 1] * sc);
        #pragma unroll
        for (int k = 0; k < 5; ++k)
            wi[q][k] = pk(w_ih[g * IN + 2 * k] * sc, w_ih[g * IN + 2 * k + 1] * sc);
        bias[q] = (bi[g] + bh[g]) * sc;
    }

    float c  = c0[(dir * BATCH + b) * H + u];
    float hv = h0[(dir * BATCH + b) * H + u];

    const int  bpbase = slot * 80;     // byte addr of lane slot*20 for ds_bpermute
    const bool odd    = (u & 1);

    // ---- x pipeline: fp32 ping-pong pending buffers (distance ~4 steps), fp16 converted bufs ----
    const float*    xrow0 = x + (size_t)(dir ? SEQ - 1 : 0) * (BATCH * IN) + b * IN;
    const ptrdiff_t xstep = dir ? -(ptrdiff_t)(BATCH * IN) : (ptrdiff_t)(BATCH * IN);

    auto load_row = [&](float2 (&p)[5], int s) {
        const int sr = min(s, SEQ - 1);
        const float2* xp = (const float2*)(xrow0 + (ptrdiff_t)sr * xstep);
        #pragma unroll
        for (int k = 0; k < 5; ++k) p[k] = xp[k];
    };
    auto cvt_row = [&](int (&xc)[5], const float2 (&p)[5]) {
        #pragma unroll
        for (int k = 0; k < 5; ++k) xc[k] = pk(p[k].x, p[k].y);
    };

    float2 pA[5], pB[5];
    int xcA[5], xcB[5];
    load_row(pA, 0);
    load_row(pB, 1);
    cvt_row(xcA, pA);          // x row 0
    load_row(pA, 2);
    cvt_row(xcB, pB);          // x row 1
    load_row(pB, 3);

    float*          optr  = out + (size_t)(dir ? SEQ - 1 : 0) * (BATCH * 2 * H) + b * (2 * H) + dir * H + u;
    const ptrdiff_t ostep = dir ? -(ptrdiff_t)(BATCH * 2 * H) : (ptrdiff_t)(BATCH * 2 * H);

    auto step = [&](const int (&xc)[5], int (&xc_refill)[5], float2 (&pend)[5], int s) {
        // ---- h broadcast, all in-register: swizzle pair -> pack fp16 -> 10 bpermutes ----
        const float hsw = i_as_f(__builtin_amdgcn_ds_swizzle(f_as_i(hv), 0x041F)); // lane^1
        const float lo  = odd ? hsw : hv;
        const float hi  = odd ? hv  : hsw;
        const int   hpi = pk(lo, hi);
        int hb[10];
        #pragma unroll
        for (int k = 0; k < 10; ++k)
            hb[k] = __builtin_amdgcn_ds_bpermute(bpbase + 8 * k, hpi);

        // ---- gates: fp16 dot2, fp32 accumulate (weights & bias pre-scaled) ----
        float acc[4];
        #pragma unroll
        for (int q = 0; q < 4; ++q) {
            float a = bias[q];
            #pragma unroll
            for (int k = 0; k < 10; ++k) a = dot2(hb[k], wh[q][k], a);
            #pragma unroll
            for (int k = 0; k < 5; ++k)  a = dot2(xc[k], wi[q][k], a);
            acc[q] = a;
        }

        // ---- x pipeline maintenance (off critical path): convert, issue next ----
        cvt_row(xc_refill, pend);      // waits on loads issued 2 steps ago
        load_row(pend, s + 4);

        // ---- nonlinearities: sigmoid = rcp(1+exp2(acc)) (scale folded into weights) ----
        const float gi = rcpf(1.0f + exp2_fast(acc[0]));
        const float gf = rcpf(1.0f + exp2_fast(acc[1]));
        const float gt = fmaf(2.0f, rcpf(1.0f + exp2_fast(acc[2])), -1.0f);
        const float go = rcpf(1.0f + exp2_fast(acc[3]));
        c = fmaf(gf, c, gi * gt);
        const float th = fmaf(2.0f, rcpf(1.0f + exp2_fast(c * (-2.0f * L2E))), -1.0f);
        hv = go * th;

        if (active) *optr = hv;
        optr += ostep;
    };

    for (int s = 0; s < SEQ; s += 2) {
        step(xcA, xcA, pA, s);        // uses x row s;   refills xcA with row s+2
        step(xcB, xcB, pB, s + 1);    // uses x row s+1; refills xcB with row s+3
    }

    if (active) {
        h_n[(dir * BATCH + b) * H + u] = hv;
        c_n[(dir * BATCH + b) * H + u] = c;
    }
}

} // namespace

extern "C" void kernel_launch(void* const* d_in, const int* in_sizes, int n_in,
                              void* d_out, int out_size, void* d_ws, size_t ws_size,
                              hipStream_t stream)
{
    const float* x      = (const float*)d_in[0];
    const float* h0     = (const float*)d_in[1];
    const float* c0     = (const float*)d_in[2];
    const float* w_ih_f = (const float*)d_in[3];
    const float* w_hh_f = (const float*)d_in[4];
    const float* b_ih_f = (const float*)d_in[5];
    const float* b_hh_f = (const float*)d_in[6];
    const float* w_ih_b = (const float*)d_in[7];
    const float* w_hh_b = (const float*)d_in[8];
    const float* b_ih_b = (const float*)d_in[9];
    const float* b_hh_b = (const float*)d_in[10];

    float* out = (float*)d_out;
    float* h_n = out + (size_t)SEQ * BATCH * 2 * H;
    float* c_n = h_n + (size_t)2 * BATCH * H;

    dim3 grid(NBLK, 2), block(64);
    hipLaunchKernelGGL(lstm_bidir, grid, block, 0, stream,
                       x, h0, c0, w_ih_f, w_hh_f, b_ih_f, b_hh_f,
                       w_ih_b, w_hh_b, b_ih_b, b_hh_b, out, h_n, c_n);
}

// Round 5
// 606.511 us; speedup vs baseline: 2.0100x; 1.3156x over previous
//
#include <hip/hip_runtime.h>

namespace {

constexpr int SEQ = 2048, BATCH = 1024, IN = 10, H = 20;
constexpr int WB   = 3;                        // batch slots per wave
constexpr int NBLK = (BATCH + WB - 1) / WB;    // 342
constexpr int XS   = 32;                       // x steps per LDS chunk
constexpr float L2E = 1.4426950408889634f;

typedef _Float16 h2t __attribute__((ext_vector_type(2)));

__device__ __forceinline__ float rcpf(float x) { return __builtin_amdgcn_rcpf(x); }
__device__ __forceinline__ float xp2(float x) {
#if __has_builtin(__builtin_amdgcn_exp2f)
    return __builtin_amdgcn_exp2f(x);
#else
    return exp2f(x);
#endif
}
// pack two f32 -> 2xfp16 in an int (v_cvt_pkrtz_f16_f32)
__device__ __forceinline__ int pk(float a, float b) {
    auto v = __builtin_amdgcn_cvt_pkrtz(a, b);
    int i; __builtin_memcpy(&i, &v, 4); return i;
}
__device__ __forceinline__ float dot2(int a, int b, float c) {
    h2t ha, hb; __builtin_memcpy(&ha, &a, 4); __builtin_memcpy(&hb, &b, 4);
#if __has_builtin(__builtin_amdgcn_fdot2)
    return __builtin_amdgcn_fdot2(ha, hb, c, false);
#else
    return c + (float)ha.x * (float)hb.x + (float)ha.y * (float)hb.y;
#endif
}

__launch_bounds__(64)
__global__ void lstm_bidir(const float* __restrict__ x,
                           const float* __restrict__ h0,
                           const float* __restrict__ c0,
                           const float* __restrict__ w_ih_f, const float* __restrict__ w_hh_f,
                           const float* __restrict__ b_ih_f, const float* __restrict__ b_hh_f,
                           const float* __restrict__ w_ih_b, const float* __restrict__ w_hh_b,
                           const float* __restrict__ b_ih_b, const float* __restrict__ b_hh_b,
                           float* __restrict__ out, float* __restrict__ h_n, float* __restrict__ c_n)
{
    const int dir  = blockIdx.y;
    const int b0   = blockIdx.x * WB;
    const int lane = threadIdx.x;
    int slot = lane / H; if (slot >= WB) slot = WB - 1;   // lanes 60..63 mirror slot 2
    const int u    = lane % H;
    const bool active = (lane < WB * H) && (b0 + lane / H < BATCH);
    const int b    = min(b0 + slot, BATCH - 1);

    const float* w_ih = dir ? w_ih_b : w_ih_f;
    const float* w_hh = dir ? w_hh_b : w_hh_f;
    const float* bi   = dir ? b_ih_b : b_ih_f;
    const float* bh   = dir ? b_hh_b : b_hh_f;

    // x chunk: [2][XS][32] f32 (30 used per step-row, 2 pad) -> lane-linear staging
    __shared__ __align__(16) float   xlds[2][XS][32];
    // h exchange: 24 fp16 per slot (20 used, 48B stride keeps 16B alignment)
    __shared__ __align__(16) _Float16 hlds[WB * 24];

    // ---- weights in registers, fp16-packed, pre-scaled by -log2e (cell gate: -2log2e) ----
    int wh[4][10], wi[4][5]; float bias[4];
    #pragma unroll
    for (int q = 0; q < 4; ++q) {
        const float sc = (q == 2) ? (-2.0f * L2E) : (-L2E);
        const int g = q * H + u;
        #pragma unroll
        for (int k = 0; k < 10; ++k)
            wh[q][k] = pk(w_hh[g * H + 2 * k] * sc, w_hh[g * H + 2 * k + 1] * sc);
        #pragma unroll
        for (int k = 0; k < 5; ++k)
            wi[q][k] = pk(w_ih[g * IN + 2 * k] * sc, w_ih[g * IN + 2 * k + 1] * sc);
        bias[q] = (bi[g] + bh[g]) * sc;
    }

    float c  = c0[(dir * BATCH + b) * H + u];
    float hv = h0[(dir * BATCH + b) * H + u];

    // ---- x chunk staging (registers -> LDS; off the per-step critical path) ----
    float4 pend[4];
    const int t_ss = lane >> 3;          // 0..7
    const int t_c4 = (lane & 7) * 4;     // 0,4,...,28
    auto issue_chunk = [&](int s0) {
        #pragma unroll
        for (int t = 0; t < 4; ++t) {
            const int ss   = t * 8 + t_ss;
            const int srow = s0 + ss;
            const int xrow = dir ? (SEQ - 1 - srow) : srow;
            const int gcol = min(b0 * IN + t_c4, BATCH * IN - 4);  // clamp (only b0=1023 hits)
            pend[t] = *(const float4*)(x + (size_t)xrow * (BATCH * IN) + gcol);
        }
    };
    auto write_chunk = [&](int buf) {
        #pragma unroll
        for (int t = 0; t < 4; ++t)
            *(float4*)&xlds[buf][t * 8 + t_ss][t_c4] = pend[t];
    };
    // at b0=1023 the clamped tail shifts slot0's x[8],x[9] by +2 elements
    const int lastfix = (b0 * IN + 32 > BATCH * IN) ? 1 : 0;

    issue_chunk(0);  write_chunk(0);
    issue_chunk(XS);                      // chunk 1 pending in registers

    float*          optr  = out + (size_t)(dir ? SEQ - 1 : 0) * (BATCH * 2 * H) + b * (2 * H) + dir * H + u;
    const ptrdiff_t ostep = dir ? -(ptrdiff_t)(BATCH * 2 * H) : (ptrdiff_t)(BATCH * 2 * H);

    const int hown = slot * 24 + u;
    const _Float16* hsl = &hlds[0] + slot * 24;

    for (int s0 = 0; s0 < SEQ; s0 += XS) {
        const int buf = (s0 / XS) & 1;
        for (int ss = 0; ss < XS; ++ss) {
            // ---- h exchange: own write then packed-pair reads (same-wave DS is in-order) ----
            hlds[hown] = (_Float16)hv;                        // ds_write_b16
            const int4 p03 = *(const int4*)(hsl);             // pairs 0..3
            const int4 p47 = *(const int4*)(hsl + 8);         // pairs 4..7
            const int2 p89 = *(const int2*)(hsl + 16);        // pairs 8,9

            // ---- x read (f32 from LDS) + pack to fp16 pairs ----
            const float2* xp = (const float2*)&xlds[buf][ss][slot * 10];
            const float2 a0 = xp[0], a1 = xp[1], a2 = xp[2], a3 = xp[3], a4 = xp[4 + lastfix];
            int xq[5];
            xq[0] = pk(a0.x, a0.y); xq[1] = pk(a1.x, a1.y); xq[2] = pk(a2.x, a2.y);
            xq[3] = pk(a3.x, a3.y); xq[4] = pk(a4.x, a4.y);

            int hp[10];
            hp[0]=p03.x; hp[1]=p03.y; hp[2]=p03.z; hp[3]=p03.w;
            hp[4]=p47.x; hp[5]=p47.y; hp[6]=p47.z; hp[7]=p47.w;
            hp[8]=p89.x; hp[9]=p89.y;

            // ---- gates: fp16 dot2, f32 accumulate (weights & bias pre-scaled) ----
            float acc[4];
            #pragma unroll
            for (int q = 0; q < 4; ++q) {
                float a = bias[q];
                #pragma unroll
                for (int k = 0; k < 10; ++k) a = dot2(hp[k], wh[q][k], a);
                #pragma unroll
                for (int k = 0; k < 5; ++k)  a = dot2(xq[k], wi[q][k], a);
                acc[q] = a;
            }

            // ---- nonlinearities: sigmoid = rcp(1+exp2(acc)); scale folded into weights ----
            const float gi = rcpf(1.0f + xp2(acc[0]));
            const float gf = rcpf(1.0f + xp2(acc[1]));
            const float gt = fmaf(2.0f, rcpf(1.0f + xp2(acc[2])), -1.0f);
            const float go = rcpf(1.0f + xp2(acc[3]));
            c = fmaf(gf, c, gi * gt);
            const float th = fmaf(2.0f, rcpf(1.0f + xp2(c * (-2.0f * L2E))), -1.0f);
            hv = go * th;

            if (active) __builtin_nontemporal_store(hv, optr);
            optr += ostep;
        }
        // ---- chunk boundary: publish pending chunk, prefetch next-next ----
        if (s0 + XS < SEQ) {
            write_chunk(buf ^ 1);                      // counted-vmcnt wait on old loads only
            if (s0 + 2 * XS < SEQ) issue_chunk(s0 + 2 * XS);
        }
    }

    if (active) {
        h_n[(dir * BATCH + b) * H + u] = hv;
        c_n[(dir * BATCH + b) * H + u] = c;
    }
}

} // namespace

extern "C" void kernel_launch(void* const* d_in, const int* in_sizes, int n_in,
                              void* d_out, int out_size, void* d_ws, size_t ws_size,
                              hipStream_t stream)
{
    const float* x      = (const float*)d_in[0];
    const float* h0     = (const float*)d_in[1];
    const float* c0     = (const float*)d_in[2];
    const float* w_ih_f = (const float*)d_in[3];
    const float* w_hh_f = (const float*)d_in[4];
    const float* b_ih_f = (const float*)d_in[5];
    const float* b_hh_f = (const float*)d_in[6];
    const float* w_ih_b = (const float*)d_in[7];
    const float* w_hh_b = (const float*)d_in[8];
    const float* b_ih_b = (const float*)d_in[9];
    const float* b_hh_b = (const float*)d_in[10];

    float* out = (float*)d_out;
    float* h_n = out + (size_t)SEQ * BATCH * 2 * H;
    float* c_n = h_n + (size_t)2 * BATCH * H;

    dim3 grid(NBLK, 2), block(64);
    hipLaunchKernelGGL(lstm_bidir, grid, block, 0, stream,
                       x, h0, c0, w_ih_f, w_hh_f, b_ih_f, b_hh_f,
                       w_ih_b, w_hh_b, b_ih_b, b_hh_b, out, h_n, c_n);
}